// Round 7
// baseline (304.955 us; speedup 1.0000x reference)
//
#include <hip/hip_runtime.h>
#include <hip/hip_bf16.h>
#include <cstddef>
#include <cstdint>

#define B_  8
#define S_  32
#define BT_ 256      // B*S
#define N_  2000
#define E_  64000
#define GH_ 32
#define H_  64
#define G4_ 256      // 4*H
#define D_  64000    // N*GH
#define NEG_SLOPE_ 0.2f
#define KC_  64      // split-K chunks; grid = 8 gate-blocks x 64 = 512 blocks

typedef __attribute__((ext_vector_type(8))) _Float16 half8;
typedef __attribute__((ext_vector_type(4))) float floatx4;

__device__ __forceinline__ float fsigmoid(float x) { return 1.0f / (1.0f + __expf(-x)); }
__device__ __forceinline__ float ftanh_(float x)   { return 1.0f - 2.0f / (__expf(2.0f * x) + 1.0f); }

// ---------------------------------------------------------------------------
// K1: zero deg + transpose x [bt][n] -> xT [n][bt]. grid 504.
// ---------------------------------------------------------------------------
__global__ __launch_bounds__(256) void k_prep(
    const float* __restrict__ x, float* __restrict__ xT, int* __restrict__ deg)
{
  const int gt = blockIdx.x * 256 + threadIdx.x;
  if (gt < N_) deg[gt] = 0;

  __shared__ float tile[32][33];
  const int TXT = (N_ + 31) / 32;  // 63
  const int t = blockIdx.x;
  if (t >= TXT * (BT_ / 32)) return;
  const int tx = threadIdx.x & 31;
  const int ty = threadIdx.x >> 5;
  const int n0  = (t % TXT) * 32;
  const int bt0 = (t / TXT) * 32;
#pragma unroll
  for (int r = 0; r < 4; ++r) {
    const int bt = bt0 + ty + r * 8;
    const int nn = n0 + tx;
    if (nn < N_) tile[ty + r * 8][tx] = x[(size_t)bt * N_ + nn];
  }
  __syncthreads();
#pragma unroll
  for (int r = 0; r < 4; ++r) {
    const int n = n0 + ty + r * 8;
    if (n < N_) xT[(size_t)n * BT_ + bt0 + tx] = tile[tx][ty + r * 8];
  }
}

// ---------------------------------------------------------------------------
// K2: degree histogram by dst. grid 250.
// ---------------------------------------------------------------------------
__global__ __launch_bounds__(256) void k_hist(
    const int* __restrict__ ei, int* __restrict__ deg)
{
  const int i = blockIdx.x * 256 + threadIdx.x;
  if (i < E_) atomicAdd(&deg[ei[E_ + i]], 1);
}

// ---------------------------------------------------------------------------
// K3: exclusive scan deg -> rowptr + cursor. 1 block.
// ---------------------------------------------------------------------------
__global__ __launch_bounds__(256) void k_scan(
    const int* __restrict__ deg, int* __restrict__ rowptr, int* __restrict__ cursor)
{
  __shared__ int tsum[256];
  const int tid = threadIdx.x;
  int v[8];
  int s = 0;
  const int base = tid * 8;
#pragma unroll
  for (int j = 0; j < 8; ++j) {
    const int idx = base + j;
    const int d = (idx < N_) ? deg[idx] : 0;
    v[j] = s;
    s += d;
  }
  tsum[tid] = s;
  __syncthreads();
  for (int off = 1; off < 256; off <<= 1) {
    int t = 0;
    if (tid >= off) t = tsum[tid - off];
    __syncthreads();
    tsum[tid] += t;
    __syncthreads();
  }
  const int ebase = tsum[tid] - s;
#pragma unroll
  for (int j = 0; j < 8; ++j) {
    const int idx = base + j;
    if (idx < N_) {
      const int r = ebase + v[j];
      rowptr[idx] = r;
      cursor[idx] = r;
    }
  }
  if (tid == 0) rowptr[N_] = E_;
}

// ---------------------------------------------------------------------------
// K4: scatter src ids into CSR buckets. grid 250.
// ---------------------------------------------------------------------------
__global__ __launch_bounds__(256) void k_scatter(
    const int* __restrict__ ei, int* __restrict__ cursor, int* __restrict__ csr_src)
{
  const int i = blockIdx.x * 256 + threadIdx.x;
  if (i >= E_) return;
  const int s = ei[i];
  const int d = ei[E_ + i];
  const int pos = atomicAdd(&cursor[d], 1);
  csr_src[pos] = s;
}

// ---------------------------------------------------------------------------
// K5: CSR gather-aggregate -> agg fp32 [n][bt]. One block per node (2000).
// ---------------------------------------------------------------------------
__global__ __launch_bounds__(256) void k_gather(
    const float* __restrict__ xT, const int* __restrict__ rowptr,
    const int* __restrict__ csr_src,
    const float* __restrict__ w_lin, const float* __restrict__ att_src,
    const float* __restrict__ att_dst, float* __restrict__ agg)
{
  const int n   = blockIdx.x;
  const int tid = threadIdx.x;
  float c_s = 0.f, c_d = 0.f;
  for (int g = 0; g < GH_; ++g) {
    const float w = w_lin[g];
    c_s += w * att_src[g];
    c_d += w * att_dst[g];
  }
  const int r0 = rowptr[n];
  const int d  = rowptr[n + 1] - r0;
  const float xn = xT[(size_t)n * BT_ + tid];
  const float cdxn = c_d * xn;
  float e = (c_s + c_d) * xn;
  e = e > 0.f ? e : NEG_SLOPE_ * e;
  const float w0 = __expf(e);
  float num = w0 * xn, den = w0;
  int pp = 0;
  for (; pp + 4 <= d; pp += 4) {
    const int s0 = csr_src[r0 + pp + 0];
    const int s1 = csr_src[r0 + pp + 1];
    const int s2 = csr_src[r0 + pp + 2];
    const int s3 = csr_src[r0 + pp + 3];
    const float x0 = xT[(size_t)s0 * BT_ + tid];
    const float x1 = xT[(size_t)s1 * BT_ + tid];
    const float x2 = xT[(size_t)s2 * BT_ + tid];
    const float x3 = xT[(size_t)s3 * BT_ + tid];
    float e0 = fmaf(c_s, x0, cdxn); e0 = e0 > 0.f ? e0 : NEG_SLOPE_ * e0;
    float e1 = fmaf(c_s, x1, cdxn); e1 = e1 > 0.f ? e1 : NEG_SLOPE_ * e1;
    float e2 = fmaf(c_s, x2, cdxn); e2 = e2 > 0.f ? e2 : NEG_SLOPE_ * e2;
    float e3 = fmaf(c_s, x3, cdxn); e3 = e3 > 0.f ? e3 : NEG_SLOPE_ * e3;
    const float w0_ = __expf(e0), w1_ = __expf(e1), w2_ = __expf(e2), w3_ = __expf(e3);
    num += w0_ * x0 + w1_ * x1 + w2_ * x2 + w3_ * x3;
    den += (w0_ + w1_) + (w2_ + w3_);
  }
  for (; pp < d; ++pp) {
    const int s = csr_src[r0 + pp];
    const float xs = xT[(size_t)s * BT_ + tid];
    float ee = fmaf(c_s, xs, cdxn);
    ee = ee > 0.f ? ee : NEG_SLOPE_ * ee;
    const float ww = __expf(ee);
    num += ww * xs;
    den += ww;
  }
  agg[(size_t)n * BT_ + tid] = num / den;
}

// ---------------------------------------------------------------------------
// K6: fp16 MFMA matmul, depth-2 software pipeline (A+B staged together).
// pre_gates[bt,j] = sum_{n,gh} W_ih[j, n*32+gh] * relu(agg[bt,n]*wl[gh]+gb[gh])
// grid (8 nb, 64 kc) = 512 blocks (2/CU). Per iter: compute node nn from
// registers only, then issue ALL loads (B 4xfloat4 + A 4xfloat) for nn+2 into
// the just-freed stage. Waiting on stage s leaves the other stage's 8 loads
// in flight (vmcnt(8)) -> ~2 iters + wave-interleave of latency hiding.
// Round-6 failure mode (A-load inside mt-loop forced vmcnt(0) drain of the
// B-prefetch every iteration -> 83 us, all pipes idle) is removed.
// ---------------------------------------------------------------------------
__global__ __launch_bounds__(256) void k_mfma(
    const float* __restrict__ W_ih, const float* __restrict__ agg,
    const float* __restrict__ w_lin, const float* __restrict__ gat_bias,
    float* __restrict__ partial)
{
  const int nb = blockIdx.x;       // 0..7  -> j in [nb*32, nb*32+32)
  const int kc = blockIdx.y;       // 0..63
  const int n0 = (N_ * kc) / KC_;
  const int n1 = (N_ * (kc + 1)) / KC_;
  const int tid  = threadIdx.x;
  const int wv   = tid >> 6;
  const int lane = tid & 63;
  const int i16  = lane & 15;
  const int q    = lane >> 4;
  const int j0   = nb * 32;

  float wlq[8], gbq[8];
#pragma unroll
  for (int j = 0; j < 8; ++j) {
    wlq[j] = w_lin[q * 8 + j];
    gbq[j] = gat_bias[q * 8 + j];
  }

  floatx4 acc[4][2];
#pragma unroll
  for (int mt = 0; mt < 4; ++mt)
#pragma unroll
    for (int nt = 0; nt < 2; ++nt)
#pragma unroll
      for (int r = 0; r < 4; ++r) acc[mt][nt][r] = 0.f;

  const float* Bp0 = W_ih + (size_t)(j0 + i16) * D_ + q * 8;
  const float* Bp1 = Bp0 + (size_t)16 * D_;
  const float* Ab  = agg + wv * 64 + i16;

  float4 Bst[2][4];
  float  Ast[2][4];

  auto issue = [&](int nn, int s) {
    const size_t off = (size_t)nn * GH_;
    Bst[s][0] = *(const float4*)(Bp0 + off);
    Bst[s][1] = *(const float4*)(Bp0 + off + 4);
    Bst[s][2] = *(const float4*)(Bp1 + off);
    Bst[s][3] = *(const float4*)(Bp1 + off + 4);
    const float* Ar = Ab + (size_t)nn * BT_;
    Ast[s][0] = Ar[0];
    Ast[s][1] = Ar[16];
    Ast[s][2] = Ar[32];
    Ast[s][3] = Ar[48];
  };

  issue(n0, 0);
  issue((n0 + 1 < n1) ? n0 + 1 : n0, 1);

#pragma unroll 1
  for (int nn = n0; nn < n1; ++nn) {
    const int s = (nn - n0) & 1;

    // pack current node's fragments from registers (waits only on stage s)
    half8 bf0, bf1;
    bf0[0] = (_Float16)Bst[s][0].x; bf0[1] = (_Float16)Bst[s][0].y;
    bf0[2] = (_Float16)Bst[s][0].z; bf0[3] = (_Float16)Bst[s][0].w;
    bf0[4] = (_Float16)Bst[s][1].x; bf0[5] = (_Float16)Bst[s][1].y;
    bf0[6] = (_Float16)Bst[s][1].z; bf0[7] = (_Float16)Bst[s][1].w;
    bf1[0] = (_Float16)Bst[s][2].x; bf1[1] = (_Float16)Bst[s][2].y;
    bf1[2] = (_Float16)Bst[s][2].z; bf1[3] = (_Float16)Bst[s][2].w;
    bf1[4] = (_Float16)Bst[s][3].x; bf1[5] = (_Float16)Bst[s][3].y;
    bf1[6] = (_Float16)Bst[s][3].z; bf1[7] = (_Float16)Bst[s][3].w;

    half8 af[4];
#pragma unroll
    for (int mt = 0; mt < 4; ++mt) {
      const float a = Ast[s][mt];
#pragma unroll
      for (int j = 0; j < 8; ++j) {
        float v = fmaf(a, wlq[j], gbq[j]);
        v = fmaxf(v, 0.f);
        af[mt][j] = (_Float16)v;
      }
    }

    // stage s registers are dead now: issue loads for nn+2 into them
    const int nf = (nn + 2 < n1) ? nn + 2 : n1 - 1;
    issue(nf, s);

#pragma unroll
    for (int mt = 0; mt < 4; ++mt) {
      acc[mt][0] = __builtin_amdgcn_mfma_f32_16x16x32_f16(af[mt], bf0, acc[mt][0], 0, 0, 0);
      acc[mt][1] = __builtin_amdgcn_mfma_f32_16x16x32_f16(af[mt], bf1, acc[mt][1], 0, 0, 0);
    }
  }

  // C/D layout: col = lane&15 (gate), row = q*4+r (bt within 16-tile)
#pragma unroll
  for (int mt = 0; mt < 4; ++mt) {
    const int bt = wv * 64 + mt * 16 + q * 4;
#pragma unroll
    for (int nt = 0; nt < 2; ++nt) {
      const int j = j0 + nt * 16 + i16;
#pragma unroll
      for (int r = 0; r < 4; ++r)
        partial[(size_t)kc * 65536 + (size_t)(bt + r) * G4_ + j] = acc[mt][nt][r];
    }
  }
}

// ---------------------------------------------------------------------------
// K7: reduce split-K partials -> pre_gates. grid 256.
// ---------------------------------------------------------------------------
__global__ __launch_bounds__(256) void k_reduce(
    const float* __restrict__ partial, float* __restrict__ pre_gates)
{
  const int o = blockIdx.x * 256 + threadIdx.x;
  float s0 = 0.f, s1 = 0.f, s2 = 0.f, s3 = 0.f;
#pragma unroll
  for (int kc = 0; kc < KC_; kc += 4) {
    s0 += partial[(size_t)(kc + 0) * 65536 + o];
    s1 += partial[(size_t)(kc + 1) * 65536 + o];
    s2 += partial[(size_t)(kc + 2) * 65536 + o];
    s3 += partial[(size_t)(kc + 3) * 65536 + o];
  }
  pre_gates[o] = (s0 + s1) + (s2 + s3);
}

// ---------------------------------------------------------------------------
// K8: LSTM recurrence + head, one block per batch b (8 blocks).
// ---------------------------------------------------------------------------
__global__ __launch_bounds__(256) void k_lstm_head(
    const float* __restrict__ pre_gates, const float* __restrict__ W_hh,
    const float* __restrict__ b_ih, const float* __restrict__ b_hh,
    const float* __restrict__ W_head, const float* __restrict__ b_head,
    float* __restrict__ out)
{
  const int b   = blockIdx.x;
  const int tid = threadIdx.x;
  __shared__ float h_s[H_];
  __shared__ float g_s[G4_];

  float wr[H_];
#pragma unroll
  for (int k = 0; k < H_; ++k) wr[k] = W_hh[(size_t)tid * H_ + k];
  float pg[S_];
#pragma unroll
  for (int t = 0; t < S_; ++t) pg[t] = pre_gates[(size_t)(b * S_ + t) * G4_ + tid];

  const float bias = b_ih[tid] + b_hh[tid];
  if (tid < H_) h_s[tid] = 0.f;
  float c = 0.f;
  __syncthreads();

  for (int t = 0; t < S_; ++t) {
    float g0 = pg[t] + bias, g1 = 0.f, g2 = 0.f, g3 = 0.f;
#pragma unroll
    for (int k = 0; k < H_; k += 4) {
      g0 = fmaf(wr[k + 0], h_s[k + 0], g0);
      g1 = fmaf(wr[k + 1], h_s[k + 1], g1);
      g2 = fmaf(wr[k + 2], h_s[k + 2], g2);
      g3 = fmaf(wr[k + 3], h_s[k + 3], g3);
    }
    g_s[tid] = (g0 + g1) + (g2 + g3);
    __syncthreads();
    if (tid < H_) {
      const float ig = fsigmoid(g_s[tid]);
      const float fg = fsigmoid(g_s[H_ + tid]);
      const float gg = ftanh_(g_s[2 * H_ + tid]);
      const float og = fsigmoid(g_s[3 * H_ + tid]);
      c = fg * c + ig * gg;
      h_s[tid] = og * ftanh_(c);
    }
    __syncthreads();
  }

  for (int n = tid; n < N_; n += 256) {
    const float4* w4 = (const float4*)(W_head + (size_t)n * H_);
    float acc = b_head[n];
#pragma unroll
    for (int qq = 0; qq < H_ / 4; ++qq) {
      const float4 w = w4[qq];
      acc += w.x * h_s[qq * 4 + 0] + w.y * h_s[qq * 4 + 1] +
             w.z * h_s[qq * 4 + 2] + w.w * h_s[qq * 4 + 3];
    }
    out[(size_t)b * N_ + n] = acc;
  }
}

// ---------------------------------------------------------------------------
extern "C" void kernel_launch(void* const* d_in, const int* in_sizes, int n_in,
                              void* d_out, int out_size, void* d_ws, size_t ws_size,
                              hipStream_t stream) {
  const float* x        = (const float*)d_in[0];
  const int*   ei       = (const int*)  d_in[1];
  const float* w_lin    = (const float*)d_in[2];
  const float* att_src  = (const float*)d_in[3];
  const float* att_dst  = (const float*)d_in[4];
  const float* gat_bias = (const float*)d_in[5];
  const float* W_ih     = (const float*)d_in[6];
  const float* W_hh     = (const float*)d_in[7];
  const float* b_ih     = (const float*)d_in[8];
  const float* b_hh     = (const float*)d_in[9];
  const float* W_head   = (const float*)d_in[10];
  const float* b_head   = (const float*)d_in[11];
  float* out = (float*)d_out;

  char* ws = (char*)d_ws;
  float* xT        = (float*)(ws + 0);          //  2,048,000
  float* agg       = (float*)(ws + 2048000);    //  2,048,000
  float* pre_gates = (float*)(ws + 4096000);    //    262,144
  int*   deg       = (int*)  (ws + 4358144);    //      8,192
  int*   rowptr    = (int*)  (ws + 4366336);    //      8,192
  int*   cursor    = (int*)  (ws + 4374528);    //      8,192
  int*   csr_src   = (int*)  (ws + 4382720);    //    256,000
  float* partial   = (float*)(ws + 4638720);    // 64*65536*4 = 16,777,216 -> 21.4 MB total

  k_prep<<<dim3(504), dim3(256), 0, stream>>>(x, xT, deg);
  k_hist<<<dim3((E_ + 255) / 256), dim3(256), 0, stream>>>(ei, deg);
  k_scan<<<dim3(1), dim3(256), 0, stream>>>(deg, rowptr, cursor);
  k_scatter<<<dim3((E_ + 255) / 256), dim3(256), 0, stream>>>(ei, cursor, csr_src);
  k_gather<<<dim3(N_), dim3(256), 0, stream>>>(
      xT, rowptr, csr_src, w_lin, att_src, att_dst, agg);
  k_mfma<<<dim3(8, KC_), dim3(256), 0, stream>>>(
      W_ih, agg, w_lin, gat_bias, partial);
  k_reduce<<<dim3(256), dim3(256), 0, stream>>>(partial, pre_gates);
  k_lstm_head<<<dim3(B_), dim3(256), 0, stream>>>(
      pre_gates, W_hh, b_ih, b_hh, W_head, b_head, out);
}

// Round 8
// 283.862 us; speedup vs baseline: 1.0743x; 1.0743x over previous
//
#include <hip/hip_runtime.h>
#include <hip/hip_bf16.h>
#include <cstddef>
#include <cstdint>

#define B_  8
#define S_  32
#define BT_ 256      // B*S
#define N_  2000
#define E_  64000
#define GH_ 32
#define H_  64
#define G4_ 256      // 4*H
#define D_  64000    // N*GH
#define NEG_SLOPE_ 0.2f
#define KC_  63      // split-K chunks of NPC_ nodes (last = 16); grid 8 x 63
#define NPC_ 32

typedef __attribute__((ext_vector_type(8))) _Float16 half8;
typedef __attribute__((ext_vector_type(4))) float floatx4;

__device__ __forceinline__ float fsigmoid(float x) { return 1.0f / (1.0f + __expf(-x)); }
__device__ __forceinline__ float ftanh_(float x)   { return 1.0f - 2.0f / (__expf(2.0f * x) + 1.0f); }

// ---------------------------------------------------------------------------
// K1: zero deg + transpose x [bt][n] -> xT [n][bt]. grid 504.
// ---------------------------------------------------------------------------
__global__ __launch_bounds__(256) void k_prep(
    const float* __restrict__ x, float* __restrict__ xT, int* __restrict__ deg)
{
  const int gt = blockIdx.x * 256 + threadIdx.x;
  if (gt < N_) deg[gt] = 0;

  __shared__ float tile[32][33];
  const int TXT = (N_ + 31) / 32;  // 63
  const int t = blockIdx.x;
  if (t >= TXT * (BT_ / 32)) return;
  const int tx = threadIdx.x & 31;
  const int ty = threadIdx.x >> 5;
  const int n0  = (t % TXT) * 32;
  const int bt0 = (t / TXT) * 32;
#pragma unroll
  for (int r = 0; r < 4; ++r) {
    const int bt = bt0 + ty + r * 8;
    const int nn = n0 + tx;
    if (nn < N_) tile[ty + r * 8][tx] = x[(size_t)bt * N_ + nn];
  }
  __syncthreads();
#pragma unroll
  for (int r = 0; r < 4; ++r) {
    const int n = n0 + ty + r * 8;
    if (n < N_) xT[(size_t)n * BT_ + bt0 + tx] = tile[tx][ty + r * 8];
  }
}

// ---------------------------------------------------------------------------
// K2: degree histogram by dst. grid 250.
// ---------------------------------------------------------------------------
__global__ __launch_bounds__(256) void k_hist(
    const int* __restrict__ ei, int* __restrict__ deg)
{
  const int i = blockIdx.x * 256 + threadIdx.x;
  if (i < E_) atomicAdd(&deg[ei[E_ + i]], 1);
}

// ---------------------------------------------------------------------------
// K3: exclusive scan deg -> rowptr + cursor. 1 block.
// ---------------------------------------------------------------------------
__global__ __launch_bounds__(256) void k_scan(
    const int* __restrict__ deg, int* __restrict__ rowptr, int* __restrict__ cursor)
{
  __shared__ int tsum[256];
  const int tid = threadIdx.x;
  int v[8];
  int s = 0;
  const int base = tid * 8;
#pragma unroll
  for (int j = 0; j < 8; ++j) {
    const int idx = base + j;
    const int d = (idx < N_) ? deg[idx] : 0;
    v[j] = s;
    s += d;
  }
  tsum[tid] = s;
  __syncthreads();
  for (int off = 1; off < 256; off <<= 1) {
    int t = 0;
    if (tid >= off) t = tsum[tid - off];
    __syncthreads();
    tsum[tid] += t;
    __syncthreads();
  }
  const int ebase = tsum[tid] - s;
#pragma unroll
  for (int j = 0; j < 8; ++j) {
    const int idx = base + j;
    if (idx < N_) {
      const int r = ebase + v[j];
      rowptr[idx] = r;
      cursor[idx] = r;
    }
  }
  if (tid == 0) rowptr[N_] = E_;
}

// ---------------------------------------------------------------------------
// K4: scatter src ids into CSR buckets. grid 250.
// ---------------------------------------------------------------------------
__global__ __launch_bounds__(256) void k_scatter(
    const int* __restrict__ ei, int* __restrict__ cursor, int* __restrict__ csr_src)
{
  const int i = blockIdx.x * 256 + threadIdx.x;
  if (i >= E_) return;
  const int s = ei[i];
  const int d = ei[E_ + i];
  const int pos = atomicAdd(&cursor[d], 1);
  csr_src[pos] = s;
}

// ---------------------------------------------------------------------------
// K5: CSR gather-aggregate -> agg fp32 [n][bt]. One block per node (2000).
// ---------------------------------------------------------------------------
__global__ __launch_bounds__(256) void k_gather(
    const float* __restrict__ xT, const int* __restrict__ rowptr,
    const int* __restrict__ csr_src,
    const float* __restrict__ w_lin, const float* __restrict__ att_src,
    const float* __restrict__ att_dst, float* __restrict__ agg)
{
  const int n   = blockIdx.x;
  const int tid = threadIdx.x;
  float c_s = 0.f, c_d = 0.f;
  for (int g = 0; g < GH_; ++g) {
    const float w = w_lin[g];
    c_s += w * att_src[g];
    c_d += w * att_dst[g];
  }
  const int r0 = rowptr[n];
  const int d  = rowptr[n + 1] - r0;
  const float xn = xT[(size_t)n * BT_ + tid];
  const float cdxn = c_d * xn;
  float e = (c_s + c_d) * xn;
  e = e > 0.f ? e : NEG_SLOPE_ * e;
  const float w0 = __expf(e);
  float num = w0 * xn, den = w0;
  int pp = 0;
  for (; pp + 4 <= d; pp += 4) {
    const int s0 = csr_src[r0 + pp + 0];
    const int s1 = csr_src[r0 + pp + 1];
    const int s2 = csr_src[r0 + pp + 2];
    const int s3 = csr_src[r0 + pp + 3];
    const float x0 = xT[(size_t)s0 * BT_ + tid];
    const float x1 = xT[(size_t)s1 * BT_ + tid];
    const float x2 = xT[(size_t)s2 * BT_ + tid];
    const float x3 = xT[(size_t)s3 * BT_ + tid];
    float e0 = fmaf(c_s, x0, cdxn); e0 = e0 > 0.f ? e0 : NEG_SLOPE_ * e0;
    float e1 = fmaf(c_s, x1, cdxn); e1 = e1 > 0.f ? e1 : NEG_SLOPE_ * e1;
    float e2 = fmaf(c_s, x2, cdxn); e2 = e2 > 0.f ? e2 : NEG_SLOPE_ * e2;
    float e3 = fmaf(c_s, x3, cdxn); e3 = e3 > 0.f ? e3 : NEG_SLOPE_ * e3;
    const float w0_ = __expf(e0), w1_ = __expf(e1), w2_ = __expf(e2), w3_ = __expf(e3);
    num += w0_ * x0 + w1_ * x1 + w2_ * x2 + w3_ * x3;
    den += (w0_ + w1_) + (w2_ + w3_);
  }
  for (; pp < d; ++pp) {
    const int s = csr_src[r0 + pp];
    const float xs = xT[(size_t)s * BT_ + tid];
    float ee = fmaf(c_s, xs, cdxn);
    ee = ee > 0.f ? ee : NEG_SLOPE_ * ee;
    const float ww = __expf(ee);
    num += ww * xs;
    den += ww;
  }
  agg[(size_t)n * BT_ + tid] = num / den;
}

// ---------------------------------------------------------------------------
// K6: fp16 MFMA matmul. A staged in LDS (ds_read/lgkmcnt decoupled from the
// global B-prefetch/vmcnt queue — round-6's drain bug); B depth-2 pipeline in
// DISTINCT named register arrays with constant indices only (round-7's
// runtime-indexed stage arrays were demoted to scratch: 184 MB WRITE_SIZE).
// grid (8 nb, 63 kc) = 504 blocks; chunk = 32 nodes (last 16), always even.
// ---------------------------------------------------------------------------
__global__ __launch_bounds__(256) void k_mfma(
    const float* __restrict__ W_ih, const float* __restrict__ agg,
    const float* __restrict__ w_lin, const float* __restrict__ gat_bias,
    float* __restrict__ partial)
{
  __shared__ float As[NPC_ * BT_];  // 32 KB
  const int nb = blockIdx.x;        // 0..7  -> j in [nb*32, nb*32+32)
  const int kc = blockIdx.y;        // 0..62
  const int n0 = kc * NPC_;
  const int nNodes = (N_ - n0 < NPC_) ? (N_ - n0) : NPC_;  // 32 or 16 (even)
  const int tid  = threadIdx.x;
  const int wv   = tid >> 6;
  const int lane = tid & 63;
  const int i16  = lane & 15;
  const int q    = lane >> 4;
  const int j0   = nb * 32;

  // stage A chunk into LDS, coalesced float4
  {
    const float4* src = (const float4*)(agg + (size_t)n0 * BT_);
    float4* dst = (float4*)As;
    const int nv = nNodes * (BT_ / 4);
    for (int i = tid; i < nv; i += 256) dst[i] = src[i];
  }

  float wlq[8], gbq[8];
#pragma unroll
  for (int j = 0; j < 8; ++j) {
    wlq[j] = w_lin[q * 8 + j];
    gbq[j] = gat_bias[q * 8 + j];
  }

  floatx4 acc[4][2];
#pragma unroll
  for (int mt = 0; mt < 4; ++mt)
#pragma unroll
    for (int nt = 0; nt < 2; ++nt)
#pragma unroll
      for (int r = 0; r < 4; ++r) acc[mt][nt][r] = 0.f;

  __syncthreads();

  const float* Bp0 = W_ih + (size_t)(j0 + i16) * D_ + (size_t)n0 * GH_ + q * 8;
  const float* Bp1 = Bp0 + (size_t)16 * D_;

  auto ldB = [&](float4* v, int nn) {
    const size_t off = (size_t)nn * GH_;
    v[0] = *(const float4*)(Bp0 + off);
    v[1] = *(const float4*)(Bp0 + off + 4);
    v[2] = *(const float4*)(Bp1 + off);
    v[3] = *(const float4*)(Bp1 + off + 4);
  };
  auto compute = [&](const float4* v, int nnl) {
    half8 bf0, bf1;
    bf0[0] = (_Float16)v[0].x; bf0[1] = (_Float16)v[0].y;
    bf0[2] = (_Float16)v[0].z; bf0[3] = (_Float16)v[0].w;
    bf0[4] = (_Float16)v[1].x; bf0[5] = (_Float16)v[1].y;
    bf0[6] = (_Float16)v[1].z; bf0[7] = (_Float16)v[1].w;
    bf1[0] = (_Float16)v[2].x; bf1[1] = (_Float16)v[2].y;
    bf1[2] = (_Float16)v[2].z; bf1[3] = (_Float16)v[2].w;
    bf1[4] = (_Float16)v[3].x; bf1[5] = (_Float16)v[3].y;
    bf1[6] = (_Float16)v[3].z; bf1[7] = (_Float16)v[3].w;
#pragma unroll
    for (int mt = 0; mt < 4; ++mt) {
      const float a = As[nnl * BT_ + wv * 64 + mt * 16 + i16];
      half8 af;
#pragma unroll
      for (int j = 0; j < 8; ++j) {
        float val = fmaf(a, wlq[j], gbq[j]);
        val = fmaxf(val, 0.f);
        af[j] = (_Float16)val;
      }
      acc[mt][0] = __builtin_amdgcn_mfma_f32_16x16x32_f16(af, bf0, acc[mt][0], 0, 0, 0);
      acc[mt][1] = __builtin_amdgcn_mfma_f32_16x16x32_f16(af, bf1, acc[mt][1], 0, 0, 0);
    }
  };

  float4 cur0[4], cur1[4], nxt0[4], nxt1[4];  // constant-indexed only -> VGPRs
  ldB(cur0, 0);
  ldB(cur1, 1);

#pragma unroll 1
  for (int nn = 0; nn < nNodes; nn += 2) {
    const int nx0 = (nn + 2 < nNodes) ? nn + 2 : nn;
    const int nx1 = (nn + 3 < nNodes) ? nn + 3 : nn + 1;
    ldB(nxt0, nx0);
    ldB(nxt1, nx1);
    compute(cur0, nn);       // waits vmcnt(8): nxt pair stays in flight
    compute(cur1, nn + 1);
#pragma unroll
    for (int i = 0; i < 4; ++i) { cur0[i] = nxt0[i]; cur1[i] = nxt1[i]; }
  }

  // C/D layout: col = lane&15 (gate), row = q*4+r (bt within 16-tile)
#pragma unroll
  for (int mt = 0; mt < 4; ++mt) {
    const int bt = wv * 64 + mt * 16 + q * 4;
#pragma unroll
    for (int nt = 0; nt < 2; ++nt) {
      const int j = j0 + nt * 16 + i16;
#pragma unroll
      for (int r = 0; r < 4; ++r)
        partial[(size_t)kc * 65536 + (size_t)(bt + r) * G4_ + j] = acc[mt][nt][r];
    }
  }
}

// ---------------------------------------------------------------------------
// K7: reduce split-K partials -> pre_gates. grid 256. (63 = 21 x 3)
// ---------------------------------------------------------------------------
__global__ __launch_bounds__(256) void k_reduce(
    const float* __restrict__ partial, float* __restrict__ pre_gates)
{
  const int o = blockIdx.x * 256 + threadIdx.x;
  float s0 = 0.f, s1 = 0.f, s2 = 0.f;
#pragma unroll
  for (int kc = 0; kc < KC_; kc += 3) {
    s0 += partial[(size_t)(kc + 0) * 65536 + o];
    s1 += partial[(size_t)(kc + 1) * 65536 + o];
    s2 += partial[(size_t)(kc + 2) * 65536 + o];
  }
  pre_gates[o] = s0 + s1 + s2;
}

// ---------------------------------------------------------------------------
// K8: LSTM recurrence + head, one block per batch b (8 blocks).
// ---------------------------------------------------------------------------
__global__ __launch_bounds__(256) void k_lstm_head(
    const float* __restrict__ pre_gates, const float* __restrict__ W_hh,
    const float* __restrict__ b_ih, const float* __restrict__ b_hh,
    const float* __restrict__ W_head, const float* __restrict__ b_head,
    float* __restrict__ out)
{
  const int b   = blockIdx.x;
  const int tid = threadIdx.x;
  __shared__ float h_s[H_];
  __shared__ float g_s[G4_];

  float wr[H_];
#pragma unroll
  for (int k = 0; k < H_; ++k) wr[k] = W_hh[(size_t)tid * H_ + k];
  float pg[S_];
#pragma unroll
  for (int t = 0; t < S_; ++t) pg[t] = pre_gates[(size_t)(b * S_ + t) * G4_ + tid];

  const float bias = b_ih[tid] + b_hh[tid];
  if (tid < H_) h_s[tid] = 0.f;
  float c = 0.f;
  __syncthreads();

  for (int t = 0; t < S_; ++t) {
    float g0 = pg[t] + bias, g1 = 0.f, g2 = 0.f, g3 = 0.f;
#pragma unroll
    for (int k = 0; k < H_; k += 4) {
      g0 = fmaf(wr[k + 0], h_s[k + 0], g0);
      g1 = fmaf(wr[k + 1], h_s[k + 1], g1);
      g2 = fmaf(wr[k + 2], h_s[k + 2], g2);
      g3 = fmaf(wr[k + 3], h_s[k + 3], g3);
    }
    g_s[tid] = (g0 + g1) + (g2 + g3);
    __syncthreads();
    if (tid < H_) {
      const float ig = fsigmoid(g_s[tid]);
      const float fg = fsigmoid(g_s[H_ + tid]);
      const float gg = ftanh_(g_s[2 * H_ + tid]);
      const float og = fsigmoid(g_s[3 * H_ + tid]);
      c = fg * c + ig * gg;
      h_s[tid] = og * ftanh_(c);
    }
    __syncthreads();
  }

  for (int n = tid; n < N_; n += 256) {
    const float4* w4 = (const float4*)(W_head + (size_t)n * H_);
    float acc = b_head[n];
#pragma unroll
    for (int qq = 0; qq < H_ / 4; ++qq) {
      const float4 w = w4[qq];
      acc += w.x * h_s[qq * 4 + 0] + w.y * h_s[qq * 4 + 1] +
             w.z * h_s[qq * 4 + 2] + w.w * h_s[qq * 4 + 3];
    }
    out[(size_t)b * N_ + n] = acc;
  }
}

// ---------------------------------------------------------------------------
extern "C" void kernel_launch(void* const* d_in, const int* in_sizes, int n_in,
                              void* d_out, int out_size, void* d_ws, size_t ws_size,
                              hipStream_t stream) {
  const float* x        = (const float*)d_in[0];
  const int*   ei       = (const int*)  d_in[1];
  const float* w_lin    = (const float*)d_in[2];
  const float* att_src  = (const float*)d_in[3];
  const float* att_dst  = (const float*)d_in[4];
  const float* gat_bias = (const float*)d_in[5];
  const float* W_ih     = (const float*)d_in[6];
  const float* W_hh     = (const float*)d_in[7];
  const float* b_ih     = (const float*)d_in[8];
  const float* b_hh     = (const float*)d_in[9];
  const float* W_head   = (const float*)d_in[10];
  const float* b_head   = (const float*)d_in[11];
  float* out = (float*)d_out;

  char* ws = (char*)d_ws;
  float* xT        = (float*)(ws + 0);          //  2,048,000
  float* agg       = (float*)(ws + 2048000);    //  2,048,000
  float* pre_gates = (float*)(ws + 4096000);    //    262,144
  int*   deg       = (int*)  (ws + 4358144);    //      8,192
  int*   rowptr    = (int*)  (ws + 4366336);    //      8,192
  int*   cursor    = (int*)  (ws + 4374528);    //      8,192
  int*   csr_src   = (int*)  (ws + 4382720);    //    256,000
  float* partial   = (float*)(ws + 4638720);    // 63*65536*4 = 16,515,072 -> 21.2 MB

  k_prep<<<dim3(504), dim3(256), 0, stream>>>(x, xT, deg);
  k_hist<<<dim3((E_ + 255) / 256), dim3(256), 0, stream>>>(ei, deg);
  k_scan<<<dim3(1), dim3(256), 0, stream>>>(deg, rowptr, cursor);
  k_scatter<<<dim3((E_ + 255) / 256), dim3(256), 0, stream>>>(ei, cursor, csr_src);
  k_gather<<<dim3(N_), dim3(256), 0, stream>>>(
      xT, rowptr, csr_src, w_lin, att_src, att_dst, agg);
  k_mfma<<<dim3(8, KC_), dim3(256), 0, stream>>>(
      W_ih, agg, w_lin, gat_bias, partial);
  k_reduce<<<dim3(256), dim3(256), 0, stream>>>(partial, pre_gates);
  k_lstm_head<<<dim3(B_), dim3(256), 0, stream>>>(
      pre_gates, W_hh, b_ih, b_hh, W_head, b_head, out);
}